// Round 1
// baseline (38.164 us; speedup 1.0000x reference)
//
#include <hip/hip_runtime.h>

namespace {

constexpr int IMG = 192;
constexpr int OX = 95;
constexpr int OY = 95;
constexpr int NPB = OX * OY;        // 9025 patches per image
constexpr int BATCH = 128;
constexpr int TOTAL = BATCH * NPB;  // 1,155,200 patches

__device__ __forceinline__ float2 cmul(float2 a, float2 b) {
    return make_float2(a.x*b.x - a.y*b.y, a.x*b.y + a.y*b.x);
}

__global__ __launch_bounds__(256) void quanv_kernel(
    const float* __restrict__ X, const float* __restrict__ W,
    float* __restrict__ out)
{
    int tid = blockIdx.x * 256 + threadIdx.x;
    if (tid >= TOTAL) return;
    int b  = tid / NPB;
    int p  = tid - b * NPB;
    int px = p / OY;
    int py = p - px * OY;

    const float* base = X + (size_t)b * (IMG*IMG) + (px*2) * IMG + py*2;

    // 4x4 patch, feature index f = di*4+dj (conv_general_dilated_patches order, C=1)
    float in[16];
#pragma unroll
    for (int di = 0; di < 4; ++di) {
        const float2* r = reinterpret_cast<const float2*>(base + di*IMG);
        float2 lo = r[0], hi = r[1];
        in[di*4+0] = lo.x; in[di*4+1] = lo.y;
        in[di*4+2] = hi.x; in[di*4+3] = hi.y;
    }

    const float INVR2 = 0.70710678118654752440f;

    // --- encoding stage: product state, one 2-vector per qubit ---
    float2 v[4][2];
#pragma unroll
    for (int q = 0; q < 3; ++q) {
        float2 u0 = make_float2(INVR2, 0.f);
        float2 u1 = make_float2(INVR2, 0.f);
#pragma unroll
        for (int i = 0; i < 5; ++i) {
            float sn, cs;
            __sincosf(0.5f * in[q*5 + i], &sn, &cs);
            if ((i & 1) == 0) {  // RZ: u0 *= e^{-i t/2}, u1 *= e^{+i t/2}
                u0 = cmul(u0, make_float2(cs, -sn));
                u1 = cmul(u1, make_float2(cs,  sn));
            } else {             // RY
                float2 n0 = make_float2(cs*u0.x - sn*u1.x, cs*u0.y - sn*u1.y);
                float2 n1 = make_float2(sn*u0.x + cs*u1.x, sn*u0.y + cs*u1.y);
                u0 = n0; u1 = n1;
            }
        }
        v[q][0] = u0; v[q][1] = u1;
    }
    {   // qubit 3: only RZ(in[15]) (indices 16..19 out of range)
        float sn, cs;
        __sincosf(0.5f * in[15], &sn, &cs);
        v[3][0] = make_float2(INVR2*cs, -INVR2*sn);
        v[3][1] = make_float2(INVR2*cs,  INVR2*sn);
    }

    // --- weights: CRZ phase factors and RY (c,s) ---
    float2 php[4], phm[4];  // e^{+i w/2}, e^{-i w/2}
    float ca[4], sa[4];
#pragma unroll
    for (int i = 0; i < 4; ++i) {
        float sn, cs;
        __sincosf(0.5f * W[i], &sn, &cs);
        php[i] = make_float2(cs,  sn);
        phm[i] = make_float2(cs, -sn);
        __sincosf(0.5f * W[4+i], &sa[i], &ca[i]);
    }

    // --- build 16-amplitude state with diagonal CRZ phases folded in ---
    // index i = i0*8 + i1*4 + i2*2 + i3  (qubit q <-> bit 3-q)
    // CRZ(w_q, control q, target (q+1)%4): control bit 1 -> e^{(target?+:-) i w_q/2}
    float2 s[16];
#pragma unroll
    for (int i0 = 0; i0 < 2; ++i0)
#pragma unroll
    for (int i1 = 0; i1 < 2; ++i1)
#pragma unroll
    for (int i2 = 0; i2 < 2; ++i2)
#pragma unroll
    for (int i3 = 0; i3 < 2; ++i3) {
        float2 t = cmul(v[0][i0], v[1][i1]);
        t = cmul(t, v[2][i2]);
        t = cmul(t, v[3][i3]);
        if (i0) t = cmul(t, i1 ? php[0] : phm[0]);
        if (i1) t = cmul(t, i2 ? php[1] : phm[1]);
        if (i2) t = cmul(t, i3 ? php[2] : phm[2]);
        if (i3) t = cmul(t, i0 ? php[3] : phm[3]);
        s[i0*8 + i1*4 + i2*2 + i3] = t;
    }

    // --- RY(W[4+j]) on qubit j (bit 3-j) ---
#pragma unroll
    for (int j = 0; j < 4; ++j) {
        const int stride = 1 << (3 - j);
        const float c = ca[j], sn = sa[j];
#pragma unroll
        for (int i = 0; i < 16; ++i) {
            if (i & stride) continue;
            float2 a  = s[i];
            float2 b2 = s[i + stride];
            s[i]          = make_float2(c*a.x - sn*b2.x, c*a.y - sn*b2.y);
            s[i + stride] = make_float2(sn*a.x + c*b2.x, sn*a.y + c*b2.y);
        }
    }

    // --- probabilities -> Z expectations ---
    float ev[4] = {0.f, 0.f, 0.f, 0.f};
#pragma unroll
    for (int i = 0; i < 16; ++i) {
        float pi = s[i].x*s[i].x + s[i].y*s[i].y;
#pragma unroll
        for (int q = 0; q < 4; ++q)
            ev[q] += ((i >> (3 - q)) & 1) ? -pi : pi;
    }

    // out flat index = (b*9025 + p)*4 + q = tid*4 + q  -> one float4 store
    reinterpret_cast<float4*>(out)[tid] = make_float4(ev[0], ev[1], ev[2], ev[3]);
}

} // namespace

extern "C" void kernel_launch(void* const* d_in, const int* in_sizes, int n_in,
                              void* d_out, int out_size, void* d_ws, size_t ws_size,
                              hipStream_t stream) {
    const float* X = (const float*)d_in[0];
    const float* W = (const float*)d_in[1];
    float* out = (float*)d_out;
    const int blocks = (TOTAL + 255) / 256;
    quanv_kernel<<<blocks, 256, 0, stream>>>(X, W, out);
}

// Round 2
// 17.456 us; speedup vs baseline: 2.1862x; 2.1862x over previous
//
#include <hip/hip_runtime.h>

namespace {

constexpr int IMG = 192;
constexpr int OX = 95;
constexpr int OY = 95;
constexpr int NPB = OX * OY;        // 9025 patches per image
constexpr int BATCH = 128;
constexpr int TOTAL = BATCH * NPB;  // 1,155,200 patches
constexpr int NWG = (TOTAL + 255) / 256;  // 4513

__device__ __forceinline__ float2 cmul(float2 a, float2 b) {
    return make_float2(a.x*b.x - a.y*b.y, a.x*b.y + a.y*b.x);
}

__global__ __launch_bounds__(256) void quanv_kernel(
    const float* __restrict__ X, const float* __restrict__ W,
    float* __restrict__ out)
{
    // Bijective XCD-chunked swizzle (m204): each XCD gets a contiguous
    // chunk of the logical tid range -> row-overlap reuse stays in one L2.
    int orig = blockIdx.x;
    constexpr int Q8 = NWG / 8, R8 = NWG % 8;
    int xcd = orig & 7, lin = orig >> 3;
    int swz = (xcd < R8 ? xcd * (Q8 + 1) : R8 * (Q8 + 1) + (xcd - R8) * Q8) + lin;

    int tid = swz * 256 + threadIdx.x;
    if (tid >= TOTAL) return;
    int b  = tid / NPB;
    int p  = tid - b * NPB;
    int px = p / OY;
    int py = p - px * OY;

    const float* base = X + (size_t)b * (IMG*IMG) + (px*2) * IMG + py*2;

    // 4x4 patch, feature f = di*4+dj
    float in[16];
#pragma unroll
    for (int di = 0; di < 4; ++di) {
        const float2* r = reinterpret_cast<const float2*>(base + di*IMG);
        float2 lo = r[0], hi = r[1];
        in[di*4+0] = lo.x; in[di*4+1] = lo.y;
        in[di*4+2] = hi.x; in[di*4+3] = hi.y;
    }

    // --- per-qubit encoding (global phase stripped, norm^2 == 2) ---
    // gates: RZ(t0) RY(t1) RZ(t2) RY(t3) RZ(t4); start (1,1)
    float m[4];
    float2 cq[4];
#pragma unroll
    for (int q = 0; q < 3; ++q) {
        float s0,c0, s1,c1, s2,c2, s3,c3, s4,c4;
        __sincosf(       in[q*5+0], &s0, &c0);
        __sincosf(0.5f * in[q*5+1], &s1, &c1);
        __sincosf(       in[q*5+2], &s2, &c2);
        __sincosf(0.5f * in[q*5+3], &s3, &c3);
        __sincosf(       in[q*5+4], &s4, &c4);
        // after RZ(t0) stripped: u0=(1,0), u1=(c0,s0); RY(t1):
        float2 u0 = make_float2(c1 - s1*c0, -s1*s0);
        float2 u1 = make_float2(s1 + c1*c0,  c1*s0);
        // RZ(t2) stripped: u1 *= e^{i t2}
        u1 = cmul(u1, make_float2(c2, s2));
        // RY(t3)
        float2 n0 = make_float2(c3*u0.x - s3*u1.x, c3*u0.y - s3*u1.y);
        float2 n1 = make_float2(s3*u0.x + c3*u1.x, s3*u0.y + c3*u1.y);
        // RZ(t4) stripped: n1 *= e^{i t4}
        n1 = cmul(n1, make_float2(c4, s4));
        m[q]  = (n0.x*n0.x + n0.y*n0.y) - (n1.x*n1.x + n1.y*n1.y);
        cq[q] = make_float2(n0.x*n1.x + n0.y*n1.y, n0.x*n1.y - n0.y*n1.x);
    }
    {   // qubit 3: only RZ(in[15]) -> v=(1, e^{i t}); m=0 exactly
        float sn, cs;
        __sincosf(in[15], &sn, &cs);
        m[3]  = 0.f;
        cq[3] = make_float2(cs, sn);
    }

    // --- weight-dependent constants (uniform across threads) ---
    float cosw[4], sinw[4], Kq[4], S4[4];
    float2 Eh[4];
#pragma unroll
    for (int k = 0; k < 4; ++k) {
        float sh, ch, sry, cry;
        __sincosf(0.5f * W[k], &sh, &ch);
        __sincosf(W[4+k], &sry, &cry);     // full angle: R'ZR = cos(th)Z - sin(th)X
        cosw[k] = ch*ch - sh*sh;
        sinw[k] = 2.f * ch * sh;
        Eh[k]   = make_float2(ch, -sh);    // e^{-i w_k/2}
        Kq[k]   = 0.5f  * cry;
        S4[k]   = 0.25f * sry;
    }

    // a(alpha, m) = (1+cos a) + (m/2)(1-cos a)  +  i*sin(a)*(1 - m/2)
    // aC_j: alpha = w_j (control role); aT_j: alpha = w_{j-1} (target role)
    float2 aC[4], aT[4];
#pragma unroll
    for (int j = 0; j < 4; ++j) {
        float hm = 0.5f * m[j];
        int jm = (j + 3) & 3;
        aC[j] = make_float2((1.f + cosw[j])  + hm * (1.f - cosw[j]),
                            sinw[j]  * (1.f - hm));
        aT[j] = make_float2((1.f + cosw[jm]) + hm * (1.f - cosw[jm]),
                            sinw[jm] * (1.f - hm));
    }

    // ev_q = 0.5 cos(ry_q) m_q - 0.25 sin(ry_q) Re(c_q e^{-i w_q/2} aC_{q-1} aT_{q+1})
    float ev[4];
#pragma unroll
    for (int q = 0; q < 4; ++q) {
        float2 t = cmul(aC[(q+3)&3], aT[(q+1)&3]);
        t = cmul(t, Eh[q]);
        float cross = cq[q].x * t.x - cq[q].y * t.y;
        ev[q] = Kq[q] * m[q] - S4[q] * cross;
    }

    reinterpret_cast<float4*>(out)[tid] = make_float4(ev[0], ev[1], ev[2], ev[3]);
}

} // namespace

extern "C" void kernel_launch(void* const* d_in, const int* in_sizes, int n_in,
                              void* d_out, int out_size, void* d_ws, size_t ws_size,
                              hipStream_t stream) {
    const float* X = (const float*)d_in[0];
    const float* W = (const float*)d_in[1];
    float* out = (float*)d_out;
    quanv_kernel<<<NWG, 256, 0, stream>>>(X, W, out);
}